// Round 1
// baseline (718.581 us; speedup 1.0000x reference)
//
#include <hip/hip_runtime.h>
#include <math.h>

#define NB 2048
#define NS 512
#define ND 96

typedef __attribute__((ext_vector_type(8))) short short8;
typedef __attribute__((ext_vector_type(4))) float floatx4;

__device__ __forceinline__ unsigned f2bfu(float f) {
    union { float f; unsigned u; } c; c.f = f;
    unsigned u = c.u;
    u += 0x7FFF + ((u >> 16) & 1);   // RNE
    return u >> 16;
}
__device__ __forceinline__ unsigned pack2(float a, float b) {
    return f2bfu(a) | (f2bfu(b) << 16);
}
__device__ __forceinline__ float lo_f(unsigned u) {
    union { unsigned u; float f; } c; c.u = u << 16; return c.f;
}
__device__ __forceinline__ float hi_f(unsigned u) {
    union { unsigned u; float f; } c; c.u = u & 0xFFFF0000u; return c.f;
}
__device__ __forceinline__ float sigm(float x) {
    return 1.0f / (1.0f + __expf(-x));
}
__device__ __forceinline__ short8 cvt8(floatx4 p0, floatx4 p1) {
    short8 v;
    v[0]=(short)f2bfu(p0[0]); v[1]=(short)f2bfu(p0[1]);
    v[2]=(short)f2bfu(p0[2]); v[3]=(short)f2bfu(p0[3]);
    v[4]=(short)f2bfu(p1[0]); v[5]=(short)f2bfu(p1[1]);
    v[6]=(short)f2bfu(p1[2]); v[7]=(short)f2bfu(p1[3]);
    return v;
}

__global__ __launch_bounds__(512, 4)
void attn_fused(const float* __restrict__ seq,   // (B,S,96)
                const float* __restrict__ tgt,   // (B,1,96)
                const int*   __restrict__ mask,  // (B,513,1) int32
                const float* __restrict__ w1,    // (96,96) [e][d]
                const float* __restrict__ b1,    // (96)
                const float* __restrict__ w2,    // (96,96) [e][d]
                const float* __restrict__ b2,    // (96)
                float* __restrict__ out)         // (B,96)
{
    // W1 staged as bf16 MFMA B-fragments: frag(t,kk) for lane L at
    // w1f[((t*3+kk)*64 + L)*8 .. +8]  — ds_read_b128, conflict-free.
    __shared__ short w1f[18 * 64 * 8];           // 18 KB
    __shared__ floatx4 thp4[ND];                 // tgt_h K-partials [e] = 4 floats
    __shared__ float red2[8];
    __shared__ float osum[8][ND];                // per-wave output partials

    const int b    = blockIdx.x;
    const int tid  = threadIdx.x;
    const int lane = tid & 63;
    const int wave = tid >> 6;
    const int l15  = lane & 15;
    const int quad = lane >> 4;

    // ---- phase 0: issue HBM work before any LDS dependency ----
    const int m = mask[(size_t)b * (NS + 1) + tid];     // s = tid (< 512)
    const float* abase = seq + ((size_t)b * NS + l15) * ND + quad * 8;

    floatx4 pre[6];                                      // tile 0 raw rows
    {
        const float* p = abase + (size_t)(wave * 64) * ND;
        #pragma unroll
        for (int kk = 0; kk < 3; ++kk) {
            pre[2 * kk]     = *(const floatx4*)(p + kk * 32);
            pre[2 * kk + 1] = *(const floatx4*)(p + kk * 32 + 4);
        }
    }

    // ---- stage W1 -> bf16 fragments in LDS ----
    for (int idx = tid; idx < 1152; idx += 512) {   // 96 rows x 12 chunks of 8
        const int e  = idx / 12;
        const int dc = idx - 12 * e;
        const int kk = dc >> 2;
        const int q  = dc & 3;
        const float* p = w1 + e * ND + kk * 32 + q * 8;
        floatx4 p0 = *(const floatx4*)(p);
        floatx4 p1 = *(const floatx4*)(p + 4);
        const int t = e >> 4, r = e & 15;
        *(short8*)&w1f[(((t * 3 + kk) * 64) + q * 16 + r) * 8] = cvt8(p0, p1);
    }

    // ---- tgt_h partials: 384 threads, e = tid>>2, K-quarter = tid&3 ----
    if (tid < 4 * ND) {
        const int e    = tid >> 2;
        const int part = tid & 3;
        const float* tv = tgt + (size_t)b * ND + part * 24;
        const float* wr = w2 + e * ND + part * 24;
        float acc = 0.f;
        #pragma unroll
        for (int d = 0; d < 24; d += 4) {
            floatx4 a = *(const floatx4*)(tv + d);
            floatx4 w = *(const floatx4*)(wr + d);
            acc += a[0]*w[0] + a[1]*w[1] + a[2]*w[2] + a[3]*w[3];
        }
        thp4[e][part] = acc;
    }
    __syncthreads();

    float tgtv[6], biasv[6];
    #pragma unroll
    for (int t = 0; t < 6; ++t) {
        const int e = 16 * t + l15;
        floatx4 tp = thp4[e];
        tgtv[t]  = b2[e] + tp[0] + tp[1] + tp[2] + tp[3];
        biasv[t] = b1[e];
    }

    // ---- main loop: each of 8 waves owns 4 s-tiles of 16 rows ----
    // lane's seq_h kept in packed-bf16 registers: pk[tile][t][0..1]
    unsigned pk[4][6][2];
    float myscore = 0.f;                 // score for s = wave*64 + lane

    #pragma unroll
    for (int sti = 0; sti < 4; ++sti) {
        const int s0 = (wave * 4 + sti) * 16;
        short8 af[3];
        if (sti == 0) {
            af[0] = cvt8(pre[0], pre[1]);
            af[1] = cvt8(pre[2], pre[3]);
            af[2] = cvt8(pre[4], pre[5]);
        } else {
            #pragma unroll
            for (int kk = 0; kk < 3; ++kk) {
                const float* p = abase + (size_t)s0 * ND + kk * 32;
                af[kk] = cvt8(*(const floatx4*)(p), *(const floatx4*)(p + 4));
            }
        }
        float p0s = 0.f, p1s = 0.f, p2s = 0.f, p3s = 0.f;
        #pragma unroll
        for (int t = 0; t < 6; ++t) {
            floatx4 acc = { biasv[t], biasv[t], biasv[t], biasv[t] };
            #pragma unroll
            for (int kk = 0; kk < 3; ++kk) {
                const short8 bf = *(const short8*)&w1f[((t * 3 + kk) * 64 + lane) * 8];
                acc = __builtin_amdgcn_mfma_f32_16x16x32_bf16(af[kk], bf, acc, 0, 0, 0);
            }
            pk[sti][t][0] = pack2(acc[0], acc[1]);
            pk[sti][t][1] = pack2(acc[2], acc[3]);
            const float thv = tgtv[t];
            p0s += sigm(acc[0] + thv);
            p1s += sigm(acc[1] + thv);
            p2s += sigm(acc[2] + thv);
            p3s += sigm(acc[3] + thv);
        }
        // reduce over the 16 lanes (e-columns) of each quad; butterfly leaves
        // the full sum in every lane of the quad
        #pragma unroll
        for (int off = 1; off < 16; off <<= 1) {
            p0s += __shfl_xor(p0s, off, 64);
            p1s += __shfl_xor(p1s, off, 64);
            p2s += __shfl_xor(p2s, off, 64);
            p3s += __shfl_xor(p3s, off, 64);
        }
        // intra-wave scatter: lane L (with L>>4 == sti) picks score for
        // s = wave*64 + L from quad (L>>2)&3, slot L&3 — no LDS, no barrier.
        float pv = p0s;
        pv = ((lane & 3) == 1) ? p1s : pv;
        pv = ((lane & 3) == 2) ? p2s : pv;
        pv = ((lane & 3) == 3) ? p3s : pv;
        const int src = (((lane >> 2) & 3) << 4) | (lane & 3);
        const float g = __shfl(pv, src, 64);
        if ((lane >> 4) == sti) myscore = g;
    }

    // ---- masked softmax, fixed-shift (scores in (0,96) so exp(v-96) is safe;
    //      shift-invariance of softmax makes this exact up to rounding) ----
    float e0 = (m != 0) ? 0.0f : __expf(myscore - 96.0f);
    float ssum = e0;
    #pragma unroll
    for (int off = 1; off < 64; off <<= 1) ssum += __shfl_xor(ssum, off, 64);
    if (lane == 0) red2[wave] = ssum;
    __syncthreads();
    float tot = red2[0];
    #pragma unroll
    for (int w = 1; w < 8; ++w) tot += red2[w];
    const float atv = e0 * (1.0f / tot);   // attn weight for s = wave*64 + lane

    // ---- output: out[b,e] = sum_s attn[s] * seq_h[s,e], register-resident ----
    float o[6] = {0.f, 0.f, 0.f, 0.f, 0.f, 0.f};
    #pragma unroll
    for (int sti = 0; sti < 4; ++sti) {
        const int sb = sti * 16 + quad * 4;
        const float a0 = __shfl(atv, sb + 0, 64);
        const float a1 = __shfl(atv, sb + 1, 64);
        const float a2 = __shfl(atv, sb + 2, 64);
        const float a3 = __shfl(atv, sb + 3, 64);
        #pragma unroll
        for (int t = 0; t < 6; ++t) {
            const unsigned u0 = pk[sti][t][0];
            const unsigned u1 = pk[sti][t][1];
            o[t] += a0 * lo_f(u0) + a1 * hi_f(u0) + a2 * lo_f(u1) + a3 * hi_f(u1);
        }
    }
    #pragma unroll
    for (int t = 0; t < 6; ++t) {
        o[t] += __shfl_xor(o[t], 16, 64);
        o[t] += __shfl_xor(o[t], 32, 64);
    }
    if (quad == 0) {
        #pragma unroll
        for (int t = 0; t < 6; ++t) osum[wave][16 * t + l15] = o[t];
    }
    __syncthreads();
    if (tid < ND) {
        float a = 0.f;
        #pragma unroll
        for (int w = 0; w < 8; ++w) a += osum[w][tid];
        out[(size_t)b * ND + tid] = a;
    }
}

extern "C" void kernel_launch(void* const* d_in, const int* in_sizes, int n_in,
                              void* d_out, int out_size, void* d_ws, size_t ws_size,
                              hipStream_t stream) {
    const float* seq  = (const float*)d_in[0];
    const float* tgt  = (const float*)d_in[1];
    const int*   mask = (const int*)d_in[2];
    const float* w1   = (const float*)d_in[3];
    const float* b1   = (const float*)d_in[4];
    const float* w2   = (const float*)d_in[5];
    const float* b2   = (const float*)d_in[6];
    float* out = (float*)d_out;
    attn_fused<<<dim3(NB), dim3(512), 0, stream>>>(seq, tgt, mask, w1, b1, w2, b2, out);
}

// Round 2
// 669.997 us; speedup vs baseline: 1.0725x; 1.0725x over previous
//
#include <hip/hip_runtime.h>
#include <math.h>

#define NB 2048
#define NS 512
#define ND 96

typedef __attribute__((ext_vector_type(8))) short short8;
typedef __attribute__((ext_vector_type(4))) float floatx4;

__device__ __forceinline__ unsigned f2bfu(float f) {
    union { float f; unsigned u; } c; c.f = f;
    unsigned u = c.u;
    u += 0x7FFF + ((u >> 16) & 1);   // RNE
    return u >> 16;
}
__device__ __forceinline__ unsigned pack2(float a, float b) {
    return f2bfu(a) | (f2bfu(b) << 16);
}
__device__ __forceinline__ float lo_f(unsigned u) {
    union { unsigned u; float f; } c; c.u = u << 16; return c.f;
}
__device__ __forceinline__ float hi_f(unsigned u) {
    union { unsigned u; float f; } c; c.u = u & 0xFFFF0000u; return c.f;
}
__device__ __forceinline__ float sigm(float x) {
    return 1.0f / (1.0f + __expf(-x));
}
__device__ __forceinline__ short8 cvt8(floatx4 p0, floatx4 p1) {
    short8 v;
    v[0]=(short)f2bfu(p0[0]); v[1]=(short)f2bfu(p0[1]);
    v[2]=(short)f2bfu(p0[2]); v[3]=(short)f2bfu(p0[3]);
    v[4]=(short)f2bfu(p1[0]); v[5]=(short)f2bfu(p1[1]);
    v[6]=(short)f2bfu(p1[2]); v[7]=(short)f2bfu(p1[3]);
    return v;
}

__global__ __launch_bounds__(512, 3)
void attn_fused(const float* __restrict__ seq,   // (B,S,96)
                const float* __restrict__ tgt,   // (B,1,96)
                const int*   __restrict__ mask,  // (B,513,1) int32
                const float* __restrict__ w1,    // (96,96) [e][d]
                const float* __restrict__ b1,    // (96)
                const float* __restrict__ w2,    // (96,96) [e][d]
                const float* __restrict__ b2,    // (96)
                float* __restrict__ out)         // (B,96)
{
    // W1 staged as bf16 MFMA B-fragments: frag(t,kk) for lane L at
    // w1f[((t*3+kk)*64 + L)*8 .. +8]  — ds_read_b128, conflict-free.
    __shared__ short w1f[18 * 64 * 8];           // 18 KB
    __shared__ floatx4 thp4[ND];                 // tgt_h K-partials [e] = 4 floats
    __shared__ float red2[8];
    __shared__ float osum[8][ND];                // per-wave output partials

    const int b    = blockIdx.x;
    const int tid  = threadIdx.x;
    const int lane = tid & 63;
    const int wave = tid >> 6;
    const int l15  = lane & 15;
    const int quad = lane >> 4;

    // early, coalesced mask load (s = tid)
    const int m = mask[(size_t)b * (NS + 1) + tid];

    // ---- stage W1 -> bf16 fragments in LDS ----
    for (int idx = tid; idx < 1152; idx += 512) {   // 96 rows x 12 chunks of 8
        const int e  = idx / 12;
        const int dc = idx - 12 * e;
        const int kk = dc >> 2;
        const int q  = dc & 3;
        const float* p = w1 + e * ND + kk * 32 + q * 8;
        floatx4 p0 = *(const floatx4*)(p);
        floatx4 p1 = *(const floatx4*)(p + 4);
        const int t = e >> 4, r = e & 15;
        *(short8*)&w1f[(((t * 3 + kk) * 64) + q * 16 + r) * 8] = cvt8(p0, p1);
    }

    // ---- tgt_h partials: 384 threads, e = tid>>2, K-quarter = tid&3 ----
    if (tid < 4 * ND) {
        const int e    = tid >> 2;
        const int part = tid & 3;
        const float* tv = tgt + (size_t)b * ND + part * 24;
        const float* wr = w2 + e * ND + part * 24;
        float acc = 0.f;
        #pragma unroll
        for (int d = 0; d < 24; d += 4) {
            floatx4 a = *(const floatx4*)(tv + d);
            floatx4 w = *(const floatx4*)(wr + d);
            acc += a[0]*w[0] + a[1]*w[1] + a[2]*w[2] + a[3]*w[3];
        }
        thp4[e][part] = acc;
    }
    __syncthreads();

    float tgtv[6], biasv[6];
    #pragma unroll
    for (int t = 0; t < 6; ++t) {
        const int e = 16 * t + l15;
        floatx4 tp = thp4[e];
        tgtv[t]  = b2[e] + tp[0] + tp[1] + tp[2] + tp[3];
        biasv[t] = b1[e];
    }

    // ---- main loop: each of 8 waves owns 4 s-tiles of 16 rows ----
    // lane's seq_h kept in packed-bf16 registers: pk[tile][t][0..1]
    const float* abase = seq + ((size_t)b * NS + l15) * ND + quad * 8;
    unsigned pk[4][6][2];
    float myscore = 0.f;                 // score for s = wave*64 + lane

    #pragma unroll
    for (int sti = 0; sti < 4; ++sti) {
        const int s0 = (wave * 4 + sti) * 16;
        short8 af[3];
        #pragma unroll
        for (int kk = 0; kk < 3; ++kk) {
            const float* p = abase + (size_t)s0 * ND + kk * 32;
            af[kk] = cvt8(*(const floatx4*)(p), *(const floatx4*)(p + 4));
        }
        float p0s = 0.f, p1s = 0.f, p2s = 0.f, p3s = 0.f;
        #pragma unroll
        for (int t = 0; t < 6; ++t) {
            floatx4 acc = { biasv[t], biasv[t], biasv[t], biasv[t] };
            #pragma unroll
            for (int kk = 0; kk < 3; ++kk) {
                const short8 bf = *(const short8*)&w1f[((t * 3 + kk) * 64 + lane) * 8];
                acc = __builtin_amdgcn_mfma_f32_16x16x32_bf16(af[kk], bf, acc, 0, 0, 0);
            }
            pk[sti][t][0] = pack2(acc[0], acc[1]);
            pk[sti][t][1] = pack2(acc[2], acc[3]);
            const float thv = tgtv[t];
            p0s += sigm(acc[0] + thv);
            p1s += sigm(acc[1] + thv);
            p2s += sigm(acc[2] + thv);
            p3s += sigm(acc[3] + thv);
        }
        // reduce over the 16 lanes (e-columns) of each quad; butterfly leaves
        // the full sum in every lane of the quad
        #pragma unroll
        for (int off = 1; off < 16; off <<= 1) {
            p0s += __shfl_xor(p0s, off, 64);
            p1s += __shfl_xor(p1s, off, 64);
            p2s += __shfl_xor(p2s, off, 64);
            p3s += __shfl_xor(p3s, off, 64);
        }
        // intra-wave scatter: lane L (with L>>4 == sti) picks score for
        // s = wave*64 + L from quad (L>>2)&3, slot L&3 — no LDS, no barrier.
        float pv = p0s;
        pv = ((lane & 3) == 1) ? p1s : pv;
        pv = ((lane & 3) == 2) ? p2s : pv;
        pv = ((lane & 3) == 3) ? p3s : pv;
        const int src = (((lane >> 2) & 3) << 4) | (lane & 3);
        const float g = __shfl(pv, src, 64);
        if ((lane >> 4) == sti) myscore = g;
    }

    // ---- masked softmax, fixed-shift (scores in (0,96) so exp(v-96) is safe;
    //      shift-invariance of softmax makes this exact up to rounding) ----
    float e0 = (m != 0) ? 0.0f : __expf(myscore - 96.0f);
    float ssum = e0;
    #pragma unroll
    for (int off = 1; off < 64; off <<= 1) ssum += __shfl_xor(ssum, off, 64);
    if (lane == 0) red2[wave] = ssum;
    __syncthreads();
    float tot = red2[0];
    #pragma unroll
    for (int w = 1; w < 8; ++w) tot += red2[w];
    const float atv = e0 * (1.0f / tot);   // attn weight for s = wave*64 + lane

    // ---- output: out[b,e] = sum_s attn[s] * seq_h[s,e], register-resident ----
    float o[6] = {0.f, 0.f, 0.f, 0.f, 0.f, 0.f};
    #pragma unroll
    for (int sti = 0; sti < 4; ++sti) {
        const int sb = sti * 16 + quad * 4;
        const float a0 = __shfl(atv, sb + 0, 64);
        const float a1 = __shfl(atv, sb + 1, 64);
        const float a2 = __shfl(atv, sb + 2, 64);
        const float a3 = __shfl(atv, sb + 3, 64);
        #pragma unroll
        for (int t = 0; t < 6; ++t) {
            const unsigned u0 = pk[sti][t][0];
            const unsigned u1 = pk[sti][t][1];
            o[t] += a0 * lo_f(u0) + a1 * hi_f(u0) + a2 * lo_f(u1) + a3 * hi_f(u1);
        }
    }
    #pragma unroll
    for (int t = 0; t < 6; ++t) {
        o[t] += __shfl_xor(o[t], 16, 64);
        o[t] += __shfl_xor(o[t], 32, 64);
    }
    if (quad == 0) {
        #pragma unroll
        for (int t = 0; t < 6; ++t) osum[wave][16 * t + l15] = o[t];
    }
    __syncthreads();
    if (tid < ND) {
        float a = 0.f;
        #pragma unroll
        for (int w = 0; w < 8; ++w) a += osum[w][tid];
        out[(size_t)b * ND + tid] = a;
    }
}

extern "C" void kernel_launch(void* const* d_in, const int* in_sizes, int n_in,
                              void* d_out, int out_size, void* d_ws, size_t ws_size,
                              hipStream_t stream) {
    const float* seq  = (const float*)d_in[0];
    const float* tgt  = (const float*)d_in[1];
    const int*   mask = (const int*)d_in[2];
    const float* w1   = (const float*)d_in[3];
    const float* b1   = (const float*)d_in[4];
    const float* w2   = (const float*)d_in[5];
    const float* b2   = (const float*)d_in[6];
    float* out = (float*)d_out;
    attn_fused<<<dim3(NB), dim3(512), 0, stream>>>(seq, tgt, mask, w1, b1, w2, b2, out);
}